// Round 4
// baseline (1749.329 us; speedup 1.0000x reference)
//
#include <hip/hip_runtime.h>
#include <hip/hip_bf16.h>
#include <math.h>

// DAGNN r4: spmm lane remap — quarter-wave per edge (4 edges per gather instr,
// 32 edges in flight per wave). bf16 propagation state, fp32 math elsewhere.

#define WAVE 64

__device__ inline float bf2f(unsigned short u) {
    union { unsigned int i; float f; } v; v.i = ((unsigned int)u) << 16; return v.f;
}
__device__ inline unsigned short f2bf(float f) {
    __hip_bfloat16 b = __float2bfloat16(f);
    union { __hip_bfloat16 b; unsigned short u; } v; v.b = b; return v.u;
}

// ---- edge dtype detection: stride 1 (int32) or 2 (int64 low words) ----
__global__ void detect_kernel(const unsigned* __restrict__ e, int* __restrict__ sflag) {
    __shared__ int any;
    if (threadIdx.x == 0) any = 0;
    __syncthreads();
    unsigned nz = 0;
    int t = threadIdx.x;
    for (int i = 0; i < 8; ++i) nz |= e[(size_t)(t * 8 + i) * 2 + 1];
    if (nz) atomicOr(&any, 1);
    __syncthreads();
    if (t == 0) *sflag = any ? 1 : 2;
}

__global__ void init_cnt_kernel(int* __restrict__ cnt, int n) {
    int i = blockIdx.x * blockDim.x + threadIdx.x;
    if (i < n) cnt[i] = 0;
}

__global__ void count_deg_kernel(const int* __restrict__ eidx, const int* __restrict__ sflag,
                                 int* __restrict__ cnt, int E) {
    int e = blockIdx.x * blockDim.x + threadIdx.x;
    int s = *sflag;
    if (e < E) {
        int c = eidx[(size_t)s * (size_t)(E + e)];
        atomicAdd(&cnt[c], 1);
    }
}

__global__ void dinv_kernel(const int* __restrict__ cnt, float* __restrict__ dinv, int n) {
    int i = blockIdx.x * blockDim.x + threadIdx.x;
    if (i < n) dinv[i] = rsqrtf((float)(cnt[i] + 1));  // self-loop adds 1
}

// ---- exclusive scan of cnt -> offs ----
__global__ void scan1_kernel(const int* __restrict__ cnt, int* __restrict__ out,
                             int* __restrict__ bsums, int n) {
    __shared__ int s[256];
    int t = threadIdx.x;
    int idx = blockIdx.x * 1024 + t * 4;
    int x0 = (idx + 0 < n) ? cnt[idx + 0] : 0;
    int x1 = (idx + 1 < n) ? cnt[idx + 1] : 0;
    int x2 = (idx + 2 < n) ? cnt[idx + 2] : 0;
    int x3 = (idx + 3 < n) ? cnt[idx + 3] : 0;
    int lsum = x0 + x1 + x2 + x3;
    s[t] = lsum;
    __syncthreads();
    for (int o = 1; o < 256; o <<= 1) {
        int v = (t >= o) ? s[t - o] : 0;
        __syncthreads();
        if (t >= o) s[t] += v;
        __syncthreads();
    }
    int excl = s[t] - lsum;
    if (idx + 0 < n) out[idx + 0] = excl;
    if (idx + 1 < n) out[idx + 1] = excl + x0;
    if (idx + 2 < n) out[idx + 2] = excl + x0 + x1;
    if (idx + 3 < n) out[idx + 3] = excl + x0 + x1 + x2;
    if (t == 255) bsums[blockIdx.x] = s[255];
}

__global__ void scan2_kernel(int* __restrict__ bsums, int nb) {
    __shared__ int s[256];
    int t = threadIdx.x;
    int v = (t < nb) ? bsums[t] : 0;
    s[t] = v;
    __syncthreads();
    for (int o = 1; o < 256; o <<= 1) {
        int x = (t >= o) ? s[t - o] : 0;
        __syncthreads();
        if (t >= o) s[t] += x;
        __syncthreads();
    }
    if (t < nb) bsums[t] = s[t] - v;
}

__global__ void scan3_kernel(int* __restrict__ offs, const int* __restrict__ bsums,
                             int* __restrict__ cursor, int n, int total) {
    int t = threadIdx.x;
    int idx = blockIdx.x * 1024 + t * 4;
    int add = bsums[blockIdx.x];
    #pragma unroll
    for (int i = 0; i < 4; ++i) {
        if (idx + i < n) {
            int v = offs[idx + i] + add;
            offs[idx + i] = v;
            cursor[idx + i] = v;
        }
    }
    if (blockIdx.x == 0 && t == 0) offs[n] = total;
}

__global__ void fill_csr_kernel(const int* __restrict__ eidx, const int* __restrict__ sflag,
                                int* __restrict__ cursor, int* __restrict__ csr_src, int E) {
    int t = blockIdx.x * blockDim.x + threadIdx.x;
    if (t >= E) return;
    int s = *sflag;
    int r = eidx[(size_t)s * (size_t)t];
    int c = eidx[(size_t)s * (size_t)(E + t)];
    int pos = atomicAdd(&cursor[c], 1);
    csr_src[pos] = r;
}

// ---- fp32 GEMM, K fixed = 256, 64x64 tile, 256 threads, 4x4 per thread ----
__global__ __launch_bounds__(256) void gemm_kernel(
        const float* __restrict__ A, int lda,
        const float* __restrict__ B, int ldb,
        const float* __restrict__ bias,
        float* __restrict__ C, int ldc,
        int M, int relu) {
    __shared__ float As[16][68];
    __shared__ float Bs[16][68];
    int tid = threadIdx.x;
    int tx = tid & 15, ty = tid >> 4;
    int bm = blockIdx.y * 64, bn = blockIdx.x * 64;
    float acc[4][4] = {};
    for (int k0 = 0; k0 < 256; k0 += 16) {
        int ka = tid & 15, ma = tid >> 4;
        #pragma unroll
        for (int p = 0; p < 4; ++p) {
            int m = ma + p * 16;
            int row = bm + m;
            As[ka][m] = (row < M) ? A[(size_t)row * lda + k0 + ka] : 0.f;
        }
        int nb_ = tid & 63, kb = tid >> 6;
        #pragma unroll
        for (int p = 0; p < 4; ++p) {
            int k = kb + p * 4;
            Bs[k][nb_] = B[(size_t)(k0 + k) * ldb + bn + nb_];
        }
        __syncthreads();
        #pragma unroll
        for (int kk = 0; kk < 16; ++kk) {
            float4 av = *(const float4*)&As[kk][ty * 4];
            float4 bv = *(const float4*)&Bs[kk][tx * 4];
            float a[4] = {av.x, av.y, av.z, av.w};
            float b[4] = {bv.x, bv.y, bv.z, bv.w};
            #pragma unroll
            for (int i = 0; i < 4; ++i)
                #pragma unroll
                for (int j = 0; j < 4; ++j)
                    acc[i][j] = fmaf(a[i], b[j], acc[i][j]);
        }
        __syncthreads();
    }
    #pragma unroll
    for (int i = 0; i < 4; ++i) {
        int row = bm + ty * 4 + i;
        if (row < M) {
            float4 o;
            o.x = acc[i][0] + bias[bn + tx * 4 + 0];
            o.y = acc[i][1] + bias[bn + tx * 4 + 1];
            o.z = acc[i][2] + bias[bn + tx * 4 + 2];
            o.w = acc[i][3] + bias[bn + tx * 4 + 3];
            if (relu) {
                o.x = fmaxf(o.x, 0.f); o.y = fmaxf(o.y, 0.f);
                o.z = fmaxf(o.z, 0.f); o.w = fmaxf(o.w, 0.f);
            }
            *(float4*)&C[(size_t)row * ldc + bn + tx * 4] = o;
        }
    }
}

// ---- hop 0: out = sigmoid(h.pw + pb)*h ; g0 = bf16(dinv*h) ----
__global__ void hop0_kernel(const float* __restrict__ h, const float* __restrict__ dinv,
                            const float* __restrict__ pw, const float* __restrict__ pb,
                            float* __restrict__ out, __hip_bfloat16* __restrict__ g, int n) {
    int wid = (blockIdx.x * blockDim.x + threadIdx.x) >> 6;
    int lane = threadIdx.x & 63;
    if (wid >= n) return;
    float v = h[(size_t)wid * 64 + lane];
    float d = v * pw[lane];
    #pragma unroll
    for (int o = 32; o > 0; o >>= 1) d += __shfl_xor(d, o, 64);
    float sg = 1.f / (1.f + __expf(-(d + pb[0])));
    out[(size_t)wid * 64 + lane] = sg * v;
    g[(size_t)wid * 64 + lane] = __float2bfloat16(dinv[wid] * v);
}

// ---- one hop, quarter-wave-per-edge layout.
// lane = q*16 + r ; q in [0,4) picks edge within group of 4; r picks channels 4r..4r+3.
// acc = sum g[src]; h = dinv[c]*(acc + g[c]); gout = bf16(dinv[c]*h);
// out += sigmoid(h.pw+pb)*h. ----
__global__ __launch_bounds__(256) void spmm_kernel(
        const int* __restrict__ offs, const int* __restrict__ src,
        const float* __restrict__ dinv,
        const unsigned short* __restrict__ gin,
        unsigned short* __restrict__ gout,
        float* __restrict__ out,
        const float* __restrict__ pw, const float* __restrict__ pb,
        int n) {
    int wid = (blockIdx.x * blockDim.x + threadIdx.x) >> 6;
    int lane = threadIdx.x & 63;
    if (wid >= n) return;
    int q = lane >> 4;
    int r = lane & 15;
    int c = __builtin_amdgcn_readfirstlane(wid);
    int e0 = __builtin_amdgcn_readfirstlane(offs[c]);
    int eend = __builtin_amdgcn_readfirstlane(offs[c + 1]);

    float4 acc = make_float4(0.f, 0.f, 0.f, 0.f);
    int e = e0;
    // full iterations: 32 edges, 8 gather instrs in flight
    for (; e + 32 <= eend; e += 32) {
        #pragma unroll
        for (int i = 0; i < 8; ++i) {
            int s = src[e + 4 * i + q];
            ushort4 u = *(const ushort4*)(gin + (size_t)s * 64 + r * 4);
            acc.x += bf2f(u.x);
            acc.y += bf2f(u.y);
            acc.z += bf2f(u.z);
            acc.w += bf2f(u.w);
        }
    }
    // masked epilogue
    #pragma unroll
    for (int i = 0; i < 8; ++i) {
        int ee = e + 4 * i + q;
        if (ee < eend) {
            int s = src[ee];
            ushort4 u = *(const ushort4*)(gin + (size_t)s * 64 + r * 4);
            acc.x += bf2f(u.x);
            acc.y += bf2f(u.y);
            acc.z += bf2f(u.z);
            acc.w += bf2f(u.w);
        }
    }
    // combine quarters (lanes with same r end up with full sums)
    acc.x += __shfl_xor(acc.x, 16, 64);
    acc.y += __shfl_xor(acc.y, 16, 64);
    acc.z += __shfl_xor(acc.z, 16, 64);
    acc.w += __shfl_xor(acc.w, 16, 64);
    acc.x += __shfl_xor(acc.x, 32, 64);
    acc.y += __shfl_xor(acc.y, 32, 64);
    acc.z += __shfl_xor(acc.z, 32, 64);
    acc.w += __shfl_xor(acc.w, 32, 64);

    // self term + scale
    ushort4 uc = *(const ushort4*)(gin + (size_t)c * 64 + r * 4);
    float dc = dinv[c];
    float4 h;
    h.x = dc * (acc.x + bf2f(uc.x));
    h.y = dc * (acc.y + bf2f(uc.y));
    h.z = dc * (acc.z + bf2f(uc.z));
    h.w = dc * (acc.w + bf2f(uc.w));

    if (q == 0) {
        ushort4 o;
        o.x = f2bf(dc * h.x);
        o.y = f2bf(dc * h.y);
        o.z = f2bf(dc * h.z);
        o.w = f2bf(dc * h.w);
        *(ushort4*)(gout + (size_t)c * 64 + r * 4) = o;
    }

    // pooling: d = sum_ch h[ch]*pw[ch]; reduce over r bits (1,2,4,8)
    float4 pwv = *(const float4*)(pw + r * 4);
    float d = h.x * pwv.x + h.y * pwv.y + h.z * pwv.z + h.w * pwv.w;
    d += __shfl_xor(d, 1, 64);
    d += __shfl_xor(d, 2, 64);
    d += __shfl_xor(d, 4, 64);
    d += __shfl_xor(d, 8, 64);
    float sg = 1.f / (1.f + __expf(-(d + pb[0])));

    if (q == 0) {
        float4 ov = *(const float4*)(out + (size_t)c * 64 + r * 4);
        ov.x += sg * h.x;
        ov.y += sg * h.y;
        ov.z += sg * h.z;
        ov.w += sg * h.w;
        *(float4*)(out + (size_t)c * 64 + r * 4) = ov;
    }
}

extern "C" void kernel_launch(void* const* d_in, const int* in_sizes, int n_in,
                              void* d_out, int out_size, void* d_ws, size_t ws_size,
                              hipStream_t stream) {
    const float* x  = (const float*)d_in[0];
    const int* eidx = (const int*)d_in[1];
    const float* W1 = (const float*)d_in[2];
    const float* b1 = (const float*)d_in[3];
    const float* W2 = (const float*)d_in[4];
    const float* b2 = (const float*)d_in[5];
    const float* pw = (const float*)d_in[6];
    const float* pb = (const float*)d_in[7];
    float* out = (float*)d_out;

    const int N = in_sizes[0] / 256;
    const int E = in_sizes[1] / 2;

    size_t woff = 0;
    auto alloc = [&](size_t bytes) -> void* {
        void* p = (char*)d_ws + woff;
        woff += (bytes + 255) & ~(size_t)255;
        return p;
    };
    int*   sflag   = (int*)alloc(4);
    int*   cnt     = (int*)alloc((size_t)N * 4);
    float* dinv    = (float*)alloc((size_t)N * 4);
    int*   offs    = (int*)alloc(((size_t)N + 1) * 4);
    int*   cursor  = (int*)alloc((size_t)N * 4);
    int*   bsums   = (int*)alloc(256 * 4);
    int*   csr_src = (int*)alloc((size_t)E * 4);
    const int CH = 25600;
    float* h1 = (float*)alloc((size_t)CH * 256 * 4);
    float* hA = (float*)alloc((size_t)N * 64 * 4);
    unsigned short* gA = (unsigned short*)alloc((size_t)N * 64 * 2);
    unsigned short* gB = (unsigned short*)alloc((size_t)N * 64 * 2);

    detect_kernel<<<1, 256, 0, stream>>>((const unsigned*)eidx, sflag);
    init_cnt_kernel<<<(N + 255) / 256, 256, 0, stream>>>(cnt, N);
    count_deg_kernel<<<(E + 255) / 256, 256, 0, stream>>>(eidx, sflag, cnt, E);
    dinv_kernel<<<(N + 255) / 256, 256, 0, stream>>>(cnt, dinv, N);
    int nb = (N + 1023) / 1024;
    scan1_kernel<<<nb, 256, 0, stream>>>(cnt, offs, bsums, N);
    scan2_kernel<<<1, 256, 0, stream>>>(bsums, nb);
    scan3_kernel<<<nb, 256, 0, stream>>>(offs, bsums, cursor, N, E);
    fill_csr_kernel<<<(E + 255) / 256, 256, 0, stream>>>(eidx, sflag, cursor, csr_src, E);

    for (int ms = 0; ms < N; ms += CH) {
        int mc = (N - ms < CH) ? (N - ms) : CH;
        dim3 g1(4, (mc + 63) / 64);
        gemm_kernel<<<g1, 256, 0, stream>>>(x + (size_t)ms * 256, 256, W1, 256, b1,
                                            h1, 256, mc, 1);
        dim3 g2(1, (mc + 63) / 64);
        gemm_kernel<<<g2, 256, 0, stream>>>(h1, 256, W2, 64, b2,
                                            hA + (size_t)ms * 64, 64, mc, 0);
    }

    int nwb = (N + 3) / 4;  // 4 waves (=4 dest nodes) per 256-thread block
    hop0_kernel<<<nwb, 256, 0, stream>>>(hA, dinv, pw, pb, out,
                                         (__hip_bfloat16*)gA, N);
    unsigned short* gin = gA;
    unsigned short* gout = gB;
    for (int k = 0; k < 10; ++k) {
        spmm_kernel<<<nwb, 256, 0, stream>>>(offs, csr_src, dinv, gin, gout, out, pw, pb, N);
        unsigned short* t = gin; gin = gout; gout = t;
    }
}

// Round 5
// 1490.946 us; speedup vs baseline: 1.1733x; 1.1733x over previous
//
#include <hip/hip_runtime.h>
#include <hip/hip_bf16.h>
#include <math.h>

// DAGNN r5: spmm reverted to r3 form (wave-per-dest, scalar edge indices,
// bf16 state). NEW: MLP GEMMs via bf16 MFMA (v_mfma_f32_32x32x16_bf16),
// fp32 accumulate, on-the-fly bf16 conversion in LDS staging. h1 kept bf16.

#define WAVE 64

__device__ inline float bf2f(unsigned short u) {
    union { unsigned int i; float f; } v; v.i = ((unsigned int)u) << 16; return v.f;
}
__device__ inline unsigned short f2bf(float f) {
    __hip_bfloat16 b = __float2bfloat16(f);
    union { __hip_bfloat16 b; unsigned short u; } v; v.b = b; return v.u;
}

typedef __attribute__((ext_vector_type(8))) short bf16x8;
typedef __attribute__((ext_vector_type(16))) float f32x16;

// ---- edge dtype detection: stride 1 (int32) or 2 (int64 low words) ----
__global__ void detect_kernel(const unsigned* __restrict__ e, int* __restrict__ sflag) {
    __shared__ int any;
    if (threadIdx.x == 0) any = 0;
    __syncthreads();
    unsigned nz = 0;
    int t = threadIdx.x;
    for (int i = 0; i < 8; ++i) nz |= e[(size_t)(t * 8 + i) * 2 + 1];
    if (nz) atomicOr(&any, 1);
    __syncthreads();
    if (t == 0) *sflag = any ? 1 : 2;
}

__global__ void init_cnt_kernel(int* __restrict__ cnt, int n) {
    int i = blockIdx.x * blockDim.x + threadIdx.x;
    if (i < n) cnt[i] = 0;
}

__global__ void count_deg_kernel(const int* __restrict__ eidx, const int* __restrict__ sflag,
                                 int* __restrict__ cnt, int E) {
    int e = blockIdx.x * blockDim.x + threadIdx.x;
    int s = *sflag;
    if (e < E) {
        int c = eidx[(size_t)s * (size_t)(E + e)];
        atomicAdd(&cnt[c], 1);
    }
}

__global__ void dinv_kernel(const int* __restrict__ cnt, float* __restrict__ dinv, int n) {
    int i = blockIdx.x * blockDim.x + threadIdx.x;
    if (i < n) dinv[i] = rsqrtf((float)(cnt[i] + 1));  // self-loop adds 1
}

// ---- exclusive scan of cnt -> offs ----
__global__ void scan1_kernel(const int* __restrict__ cnt, int* __restrict__ out,
                             int* __restrict__ bsums, int n) {
    __shared__ int s[256];
    int t = threadIdx.x;
    int idx = blockIdx.x * 1024 + t * 4;
    int x0 = (idx + 0 < n) ? cnt[idx + 0] : 0;
    int x1 = (idx + 1 < n) ? cnt[idx + 1] : 0;
    int x2 = (idx + 2 < n) ? cnt[idx + 2] : 0;
    int x3 = (idx + 3 < n) ? cnt[idx + 3] : 0;
    int lsum = x0 + x1 + x2 + x3;
    s[t] = lsum;
    __syncthreads();
    for (int o = 1; o < 256; o <<= 1) {
        int v = (t >= o) ? s[t - o] : 0;
        __syncthreads();
        if (t >= o) s[t] += v;
        __syncthreads();
    }
    int excl = s[t] - lsum;
    if (idx + 0 < n) out[idx + 0] = excl;
    if (idx + 1 < n) out[idx + 1] = excl + x0;
    if (idx + 2 < n) out[idx + 2] = excl + x0 + x1;
    if (idx + 3 < n) out[idx + 3] = excl + x0 + x1 + x2;
    if (t == 255) bsums[blockIdx.x] = s[255];
}

__global__ void scan2_kernel(int* __restrict__ bsums, int nb) {
    __shared__ int s[256];
    int t = threadIdx.x;
    int v = (t < nb) ? bsums[t] : 0;
    s[t] = v;
    __syncthreads();
    for (int o = 1; o < 256; o <<= 1) {
        int x = (t >= o) ? s[t - o] : 0;
        __syncthreads();
        if (t >= o) s[t] += x;
        __syncthreads();
    }
    if (t < nb) bsums[t] = s[t] - v;
}

__global__ void scan3_kernel(int* __restrict__ offs, const int* __restrict__ bsums,
                             int* __restrict__ cursor, int n, int total) {
    int t = threadIdx.x;
    int idx = blockIdx.x * 1024 + t * 4;
    int add = bsums[blockIdx.x];
    #pragma unroll
    for (int i = 0; i < 4; ++i) {
        if (idx + i < n) {
            int v = offs[idx + i] + add;
            offs[idx + i] = v;
            cursor[idx + i] = v;
        }
    }
    if (blockIdx.x == 0 && t == 0) offs[n] = total;
}

__global__ void fill_csr_kernel(const int* __restrict__ eidx, const int* __restrict__ sflag,
                                int* __restrict__ cursor, int* __restrict__ csr_src, int E) {
    int t = blockIdx.x * blockDim.x + threadIdx.x;
    if (t >= E) return;
    int s = *sflag;
    int r = eidx[(size_t)s * (size_t)t];
    int c = eidx[(size_t)s * (size_t)(E + t)];
    int pos = atomicAdd(&cursor[c], 1);
    csr_src[pos] = r;
}

// ---- bf16 MFMA GEMM. BM=128, BN=64, BK=32, 256 thr (2x2 waves), K fixed 256.
// A: fp32 (A_IS_F32) or bf16, row-major, converted during LDS staging.
// B: fp32 row-major, transposed+converted to LDS. Out: bf16 or fp32. ----
template<int A_IS_F32, int RELU, int OUT_F32>
__global__ __launch_bounds__(256) void mfma_gemm(
        const void* __restrict__ Aptr, int lda,
        const float* __restrict__ B, int ldb,
        const float* __restrict__ bias,
        void* __restrict__ Cptr, int ldc,
        int M) {
    __shared__ unsigned short Asub[128][40];   // pad to 40 (80 B rows, 16B-aligned)
    __shared__ unsigned short Bsub[64][40];    // transposed: [n][k]
    int tid = threadIdx.x;
    int wave = tid >> 6, lane = tid & 63;
    int wm = wave >> 1, wn = wave & 1;
    int bm = blockIdx.x * 128, bn = blockIdx.y * 64;
    int half = lane >> 5, l31 = lane & 31;

    f32x16 acc[2] = {};

    for (int k0 = 0; k0 < 256; k0 += 32) {
        if (A_IS_F32) {
            const float* A = (const float*)Aptr;
            #pragma unroll
            for (int i = 0; i < 4; ++i) {
                int f = i * 256 + tid;               // 0..1023 float4 slots
                int row = f >> 3, c4 = (f & 7) * 4;
                int grow = bm + row;
                float4 v = make_float4(0.f, 0.f, 0.f, 0.f);
                if (grow < M) v = *(const float4*)((const float*)A + (size_t)grow * lda + k0 + c4);
                ushort4 uu;
                uu.x = f2bf(v.x); uu.y = f2bf(v.y); uu.z = f2bf(v.z); uu.w = f2bf(v.w);
                *(ushort4*)&Asub[row][c4] = uu;
            }
        } else {
            const unsigned short* A = (const unsigned short*)Aptr;
            #pragma unroll
            for (int i = 0; i < 2; ++i) {
                int f = i * 256 + tid;               // 0..511 ushort8 slots
                int row = f >> 2, c8 = (f & 3) * 8;
                int grow = bm + row;
                ushort4 a = make_ushort4(0, 0, 0, 0), b = a;
                if (grow < M) {
                    const unsigned short* p = A + (size_t)grow * lda + k0 + c8;
                    a = *(const ushort4*)(p);
                    b = *(const ushort4*)(p + 4);
                }
                *(ushort4*)&Asub[row][c8] = a;
                *(ushort4*)&Asub[row][c8 + 4] = b;
            }
        }
        {   // B tile 32(k) x 64(n), transpose into Bsub[n][k]
            int k = tid >> 3, n0 = (tid & 7) * 8;
            const float* bp = B + (size_t)(k0 + k) * ldb + bn + n0;
            #pragma unroll
            for (int j = 0; j < 8; ++j) Bsub[n0 + j][k] = f2bf(bp[j]);
        }
        __syncthreads();
        #pragma unroll
        for (int ks = 0; ks < 32; ks += 16) {
            bf16x8 a0 = *(bf16x8*)&Asub[wm * 64 + l31][ks + half * 8];
            bf16x8 a1 = *(bf16x8*)&Asub[wm * 64 + 32 + l31][ks + half * 8];
            bf16x8 bf = *(bf16x8*)&Bsub[wn * 32 + l31][ks + half * 8];
            acc[0] = __builtin_amdgcn_mfma_f32_32x32x16_bf16(a0, bf, acc[0], 0, 0, 0);
            acc[1] = __builtin_amdgcn_mfma_f32_32x32x16_bf16(a1, bf, acc[1], 0, 0, 0);
        }
        __syncthreads();
    }

    int col = bn + wn * 32 + l31;
    float bv = bias[col];
    #pragma unroll
    for (int mt = 0; mt < 2; ++mt) {
        #pragma unroll
        for (int reg = 0; reg < 16; ++reg) {
            int rowin = (reg & 3) + 8 * (reg >> 2) + 4 * half;
            int grow = bm + wm * 64 + mt * 32 + rowin;
            if (grow < M) {
                float v = acc[mt][reg] + bv;
                if (RELU) v = fmaxf(v, 0.f);
                if (OUT_F32) ((float*)Cptr)[(size_t)grow * ldc + col] = v;
                else ((unsigned short*)Cptr)[(size_t)grow * ldc + col] = f2bf(v);
            }
        }
    }
}

// ---- hop 0: out = sigmoid(h.pw + pb)*h ; g0 = bf16(dinv*h) ----
__global__ void hop0_kernel(const float* __restrict__ h, const float* __restrict__ dinv,
                            const float* __restrict__ pw, const float* __restrict__ pb,
                            float* __restrict__ out, __hip_bfloat16* __restrict__ g, int n) {
    int wid = (blockIdx.x * blockDim.x + threadIdx.x) >> 6;
    int lane = threadIdx.x & 63;
    if (wid >= n) return;
    float v = h[(size_t)wid * 64 + lane];
    float d = v * pw[lane];
    #pragma unroll
    for (int o = 32; o > 0; o >>= 1) d += __shfl_xor(d, o, 64);
    float sg = 1.f / (1.f + __expf(-(d + pb[0])));
    out[(size_t)wid * 64 + lane] = sg * v;
    g[(size_t)wid * 64 + lane] = __float2bfloat16(dinv[wid] * v);
}

// ---- one hop (r3 form): wave per dest, scalar uniform edge indices,
// bf16 gathers, fp32 accumulate, fused pooling ----
__global__ void spmm_kernel(const int* __restrict__ offs, const int* __restrict__ src,
                            const float* __restrict__ dinv,
                            const __hip_bfloat16* __restrict__ gin,
                            __hip_bfloat16* __restrict__ gout,
                            float* __restrict__ out,
                            const float* __restrict__ pw, const float* __restrict__ pb,
                            int n) {
    int wid = (blockIdx.x * blockDim.x + threadIdx.x) >> 6;
    int lane = threadIdx.x & 63;
    if (wid >= n) return;
    int c = __builtin_amdgcn_readfirstlane(wid);
    int e = __builtin_amdgcn_readfirstlane(offs[c]);
    int eend = __builtin_amdgcn_readfirstlane(offs[c + 1]);
    float acc = 0.f;
    while (e < eend && (e & 3)) {
        acc += __bfloat162float(gin[(size_t)src[e] * 64 + lane]);
        ++e;
    }
    for (; e + 7 < eend; e += 8) {
        int4 sa = *(const int4*)(src + e);
        int4 sb = *(const int4*)(src + e + 4);
        float v0 = __bfloat162float(gin[(size_t)sa.x * 64 + lane]);
        float v1 = __bfloat162float(gin[(size_t)sa.y * 64 + lane]);
        float v2 = __bfloat162float(gin[(size_t)sa.z * 64 + lane]);
        float v3 = __bfloat162float(gin[(size_t)sa.w * 64 + lane]);
        float v4 = __bfloat162float(gin[(size_t)sb.x * 64 + lane]);
        float v5 = __bfloat162float(gin[(size_t)sb.y * 64 + lane]);
        float v6 = __bfloat162float(gin[(size_t)sb.z * 64 + lane]);
        float v7 = __bfloat162float(gin[(size_t)sb.w * 64 + lane]);
        acc += ((v0 + v1) + (v2 + v3)) + ((v4 + v5) + (v6 + v7));
    }
    for (; e + 3 < eend; e += 4) {
        int4 sa = *(const int4*)(src + e);
        float v0 = __bfloat162float(gin[(size_t)sa.x * 64 + lane]);
        float v1 = __bfloat162float(gin[(size_t)sa.y * 64 + lane]);
        float v2 = __bfloat162float(gin[(size_t)sa.z * 64 + lane]);
        float v3 = __bfloat162float(gin[(size_t)sa.w * 64 + lane]);
        acc += (v0 + v1) + (v2 + v3);
    }
    for (; e < eend; ++e) acc += __bfloat162float(gin[(size_t)src[e] * 64 + lane]);

    float dc = dinv[c];
    float h = dc * (acc + __bfloat162float(gin[(size_t)c * 64 + lane]));
    gout[(size_t)c * 64 + lane] = __float2bfloat16(dc * h);
    float d = h * pw[lane];
    #pragma unroll
    for (int o = 32; o > 0; o >>= 1) d += __shfl_xor(d, o, 64);
    float sg = 1.f / (1.f + __expf(-(d + pb[0])));
    out[(size_t)c * 64 + lane] += sg * h;
}

extern "C" void kernel_launch(void* const* d_in, const int* in_sizes, int n_in,
                              void* d_out, int out_size, void* d_ws, size_t ws_size,
                              hipStream_t stream) {
    const float* x  = (const float*)d_in[0];
    const int* eidx = (const int*)d_in[1];
    const float* W1 = (const float*)d_in[2];
    const float* b1 = (const float*)d_in[3];
    const float* W2 = (const float*)d_in[4];
    const float* b2 = (const float*)d_in[5];
    const float* pw = (const float*)d_in[6];
    const float* pb = (const float*)d_in[7];
    float* out = (float*)d_out;

    const int N = in_sizes[0] / 256;
    const int E = in_sizes[1] / 2;

    size_t woff = 0;
    auto alloc = [&](size_t bytes) -> void* {
        void* p = (char*)d_ws + woff;
        woff += (bytes + 255) & ~(size_t)255;
        return p;
    };
    int*   sflag   = (int*)alloc(4);
    int*   cnt     = (int*)alloc((size_t)N * 4);
    float* dinv    = (float*)alloc((size_t)N * 4);
    int*   offs    = (int*)alloc(((size_t)N + 1) * 4);
    int*   cursor  = (int*)alloc((size_t)N * 4);
    int*   bsums   = (int*)alloc(256 * 4);
    int*   csr_src = (int*)alloc((size_t)E * 4);
    const int CH = 25600;                       // multiple of 128
    unsigned short* h1 = (unsigned short*)alloc((size_t)CH * 256 * 2);  // bf16
    float* hA = (float*)alloc((size_t)N * 64 * 4);
    __hip_bfloat16* gA = (__hip_bfloat16*)alloc((size_t)N * 64 * 2);
    __hip_bfloat16* gB = (__hip_bfloat16*)alloc((size_t)N * 64 * 2);

    detect_kernel<<<1, 256, 0, stream>>>((const unsigned*)eidx, sflag);
    init_cnt_kernel<<<(N + 255) / 256, 256, 0, stream>>>(cnt, N);
    count_deg_kernel<<<(E + 255) / 256, 256, 0, stream>>>(eidx, sflag, cnt, E);
    dinv_kernel<<<(N + 255) / 256, 256, 0, stream>>>(cnt, dinv, N);
    int nb = (N + 1023) / 1024;
    scan1_kernel<<<nb, 256, 0, stream>>>(cnt, offs, bsums, N);
    scan2_kernel<<<1, 256, 0, stream>>>(bsums, nb);
    scan3_kernel<<<nb, 256, 0, stream>>>(offs, bsums, cursor, N, E);
    fill_csr_kernel<<<(E + 255) / 256, 256, 0, stream>>>(eidx, sflag, cursor, csr_src, E);

    for (int ms = 0; ms < N; ms += CH) {
        int mc = (N - ms < CH) ? (N - ms) : CH;
        int gb = (mc + 127) / 128;
        dim3 g1(gb, 4);   // N=256 -> 4 col-blocks of 64
        mfma_gemm<1, 1, 0><<<g1, 256, 0, stream>>>(
            x + (size_t)ms * 256, 256, W1, 256, b1, h1, 256, mc);
        dim3 g2(gb, 1);   // N=64
        mfma_gemm<0, 0, 1><<<g2, 256, 0, stream>>>(
            h1, 256, W2, 64, b2, hA + (size_t)ms * 64, 64, mc);
    }

    int nwb = (N + 3) / 4;  // 4 waves (=4 dest nodes) per 256-thread block
    hop0_kernel<<<nwb, 256, 0, stream>>>(hA, dinv, pw, pb, out, gA, N);
    __hip_bfloat16* gin = gA;
    __hip_bfloat16* gout = gB;
    for (int k = 0; k < 10; ++k) {
        spmm_kernel<<<nwb, 256, 0, stream>>>(offs, csr_src, dinv, gin, gout, out, pw, pb, N);
        __hip_bfloat16* t = gin; gin = gout; gout = t;
    }
}